// Round 1
// baseline (925.888 us; speedup 1.0000x reference)
//
#include <hip/hip_runtime.h>
#include <hip/hip_bf16.h>
#include <math.h>

// ---------------------------------------------------------------------------
// MAMIL: conv stack + fc + sparse neighbor attention + template/global attn
// Round 1: correct fp32 implementation.
//   - conv1+pool+conv2+pool fused per-instance in LDS
//   - neighbor attention computed sparsely (8-neighborhood on 32x64 grid)
//   - dense GEMMs: 64x64 tile, 4x4 microtile fp32
// ---------------------------------------------------------------------------

// ---------------- fused conv1+relu+pool -> conv2+relu+pool ----------------
__global__ __launch_bounds__(256) void conv_fused_kernel(
    const float* __restrict__ x,   // [2048,32,32]
    const float* __restrict__ w1,  // [36,16]
    const float* __restrict__ b1,  // [36]
    const float* __restrict__ w2,  // [48,36,9]
    const float* __restrict__ b2,  // [48]
    float* __restrict__ out)       // [2048,1728]
{
    __shared__ float sx[1024];
    __shared__ float sw1[576];
    __shared__ float sh1[7056];    // 36*14*14
    const int n = blockIdx.x;
    const int tid = threadIdx.x;
    for (int i = tid; i < 1024; i += 256) sx[i] = x[n*1024 + i];
    for (int i = tid; i < 576;  i += 256) sw1[i] = w1[i];
    __syncthreads();
    // conv1 (4x4, VALID -> 29x29) + relu + 2x2 maxpool -> 14x14, 36 ch
    for (int o = tid; o < 7056; o += 256) {
        const int c = o / 196;
        const int r = o % 196;
        const int py = r / 14, px = r % 14;
        const float* wp = &sw1[c*16];
        const float bb = b1[c];
        float m = -1e30f;
        #pragma unroll
        for (int dy = 0; dy < 2; ++dy)
        #pragma unroll
        for (int dx = 0; dx < 2; ++dx) {
            const int oy = 2*py + dy, ox = 2*px + dx;
            float s = bb;
            #pragma unroll
            for (int ky = 0; ky < 4; ++ky)
            #pragma unroll
            for (int kx = 0; kx < 4; ++kx)
                s = fmaf(sx[(oy+ky)*32 + ox+kx], wp[ky*4+kx], s);
            m = fmaxf(m, s);
        }
        sh1[o] = fmaxf(m, 0.0f);   // relu(max) == max(relu)
    }
    __syncthreads();
    // conv2 (36->48, 3x3, VALID -> 12x12) + relu + 2x2 maxpool -> 6x6
    for (int o = tid; o < 1728; o += 256) {
        const int c = o / 36;
        const int r = o % 36;
        const int py = r / 6, px = r % 6;
        const float* wp = &w2[c*324];
        const int oy = 2*py, ox = 2*px;
        float s0, s1, s2, s3;
        s0 = s1 = s2 = s3 = b2[c];
        for (int ic = 0; ic < 36; ++ic) {
            float wr[9];
            #pragma unroll
            for (int q = 0; q < 9; ++q) wr[q] = wp[ic*9 + q];
            const float* hp = &sh1[ic*196 + oy*14 + ox];
            #pragma unroll
            for (int ky = 0; ky < 3; ++ky)
            #pragma unroll
            for (int kx = 0; kx < 3; ++kx) {
                const float w = wr[ky*3+kx];
                s0 = fmaf(hp[ ky   *14 + kx    ], w, s0);
                s1 = fmaf(hp[ ky   *14 + kx + 1], w, s1);
                s2 = fmaf(hp[(ky+1)*14 + kx    ], w, s2);
                s3 = fmaf(hp[(ky+1)*14 + kx + 1], w, s3);
            }
        }
        const float m = fmaxf(fmaxf(s0, s1), fmaxf(s2, s3));
        out[(size_t)n*1728 + o] = fmaxf(m, 0.0f);
    }
}

// ---------------- C[M,N] = act(A[M,K] @ W[N,K]^T + bias) ----------------
// ACT: 0 = none, 1 = relu, 2 = tanh.  Requires M%64==0, N%64==0, K%16==0.
template<int ACT>
__global__ __launch_bounds__(256) void gemm_bias_act(
    const float* __restrict__ A, const float* __restrict__ W,
    const float* __restrict__ bias, float* __restrict__ C,
    const int N, const int K)
{
    __shared__ float sA[16][68];
    __shared__ float sB[16][68];
    const int bn = blockIdx.x, bm = blockIdx.y;
    const int tid = threadIdx.x;
    const int tx = tid & 15, ty = tid >> 4;
    const int lr = tid >> 2;            // 0..63
    const int lk = (tid & 3) << 2;      // 0,4,8,12
    const float* Ap = A + (size_t)(bm*64 + lr)*K + lk;
    const float* Wp = W + (size_t)(bn*64 + lr)*K + lk;
    float acc[4][4] = {};
    for (int k0 = 0; k0 < K; k0 += 16) {
        const float4 a4 = *(const float4*)(Ap + k0);
        const float4 w4 = *(const float4*)(Wp + k0);
        sA[lk+0][lr] = a4.x; sA[lk+1][lr] = a4.y; sA[lk+2][lr] = a4.z; sA[lk+3][lr] = a4.w;
        sB[lk+0][lr] = w4.x; sB[lk+1][lr] = w4.y; sB[lk+2][lr] = w4.z; sB[lk+3][lr] = w4.w;
        __syncthreads();
        #pragma unroll
        for (int kk = 0; kk < 16; ++kk) {
            float av[4], wv[4];
            #pragma unroll
            for (int i = 0; i < 4; ++i) av[i] = sA[kk][ty*4+i];
            #pragma unroll
            for (int j = 0; j < 4; ++j) wv[j] = sB[kk][tx*4+j];
            #pragma unroll
            for (int i = 0; i < 4; ++i)
            #pragma unroll
            for (int j = 0; j < 4; ++j)
                acc[i][j] = fmaf(av[i], wv[j], acc[i][j]);
        }
        __syncthreads();
    }
    const int row = bm*64 + ty*4;
    const int col = bn*64 + tx*4;
    #pragma unroll
    for (int i = 0; i < 4; ++i)
    #pragma unroll
    for (int j = 0; j < 4; ++j) {
        float v = acc[i][j] + bias[col+j];
        if (ACT == 1) v = fmaxf(v, 0.0f);
        if (ACT == 2) v = tanhf(v);
        C[(size_t)(row+i)*N + col+j] = v;
    }
}

// ---------------- sparse neighborhood attention ----------------
// one wave per node; 8-neighborhood on the 32x64 grid (always non-empty)
__global__ __launch_bounds__(64) void nbr_attn_kernel(
    const float* __restrict__ H,   // [2048,512]
    const float* __restrict__ An,  // [2048,512]
    float* __restrict__ H2)        // [2048,1024] = [H | Hn]
{
    const int i = blockIdx.x;
    const int lane = threadIdx.x;
    const int r = i >> 6, c = i & 63;
    int nbr[8]; int nn = 0;
    for (int dr = -1; dr <= 1; ++dr)
    for (int dc = -1; dc <= 1; ++dc) {
        if (dr == 0 && dc == 0) continue;
        const int rr = r + dr, cc = c + dc;
        if (rr >= 0 && rr < 32 && cc >= 0 && cc < 64) nbr[nn++] = rr*64 + cc;
    }
    float hi[8];
    #pragma unroll
    for (int q = 0; q < 8; ++q) hi[q] = H[(size_t)i*512 + q*64 + lane];
    float logits[8];
    for (int j = 0; j < nn; ++j) {
        const float* an = An + (size_t)nbr[j]*512;
        float s = 0.0f;
        #pragma unroll
        for (int q = 0; q < 8; ++q) s = fmaf(hi[q], an[q*64+lane], s);
        for (int off = 32; off; off >>= 1) s += __shfl_xor(s, off);
        logits[j] = s;
    }
    float mx = -1e30f;
    for (int j = 0; j < nn; ++j) mx = fmaxf(mx, logits[j]);
    float sum = 0.0f; float al[8];
    for (int j = 0; j < nn; ++j) { al[j] = expf(logits[j]-mx); sum += al[j]; }
    const float inv = 1.0f/sum;
    float hn[8] = {};
    for (int j = 0; j < nn; ++j) {
        const float* hj = H + (size_t)nbr[j]*512;
        const float a = al[j]*inv;
        #pragma unroll
        for (int q = 0; q < 8; ++q) hn[q] = fmaf(a, hj[q*64+lane], hn[q]);
    }
    #pragma unroll
    for (int q = 0; q < 8; ++q) {
        H2[(size_t)i*1024 + q*64 + lane]       = hi[q];
        H2[(size_t)i*1024 + 512 + q*64 + lane] = hn[q];
    }
}

// ---------------- S[n,t] = P[n,:] . templates[t,:] ----------------
__global__ __launch_bounds__(64) void template_scores_kernel(
    const float* __restrict__ P,   // [2048,1024]
    const float* __restrict__ Tm,  // [10,1024]
    float* __restrict__ S)         // [2048,10]
{
    const int n = blockIdx.x;
    const int lane = threadIdx.x;
    float p[16];
    #pragma unroll
    for (int q = 0; q < 16; ++q) p[q] = P[(size_t)n*1024 + q*64 + lane];
    for (int t = 0; t < 10; ++t) {
        const float* tm = Tm + t*1024;
        float s = 0.0f;
        #pragma unroll
        for (int q = 0; q < 16; ++q) s = fmaf(p[q], tm[q*64+lane], s);
        for (int off = 32; off; off >>= 1) s += __shfl_xor(s, off);
        if (lane == 0) S[n*10 + t] = s;
    }
}

// ---------------- betas[t,:] = softmax_n(S[:,t]) ----------------
__global__ __launch_bounds__(256) void beta_softmax_kernel(
    const float* __restrict__ S, float* __restrict__ betas)
{
    const int t = blockIdx.x;
    __shared__ float red[256];
    const int tid = threadIdx.x;
    float mx = -1e30f;
    for (int n = tid; n < 2048; n += 256) mx = fmaxf(mx, S[n*10+t]);
    red[tid] = mx; __syncthreads();
    for (int s = 128; s; s >>= 1) { if (tid < s) red[tid] = fmaxf(red[tid], red[tid+s]); __syncthreads(); }
    mx = red[0]; __syncthreads();
    float sum = 0.0f;
    for (int n = tid; n < 2048; n += 256) sum += expf(S[n*10+t]-mx);
    red[tid] = sum; __syncthreads();
    for (int s = 128; s; s >>= 1) { if (tid < s) red[tid] += red[tid+s]; __syncthreads(); }
    const float inv = 1.0f/red[0];
    for (int n = tid; n < 2048; n += 256) betas[t*2048+n] = expf(S[n*10+t]-mx)*inv;
}

__global__ __launch_bounds__(256) void zero_kernel(float* p, int n)
{
    const int i = blockIdx.x*256 + threadIdx.x;
    if (i < n) p[i] = 0.0f;
}

// ---------------- embs[t,:] += betas[t,chunk] @ H2[chunk,:] ----------------
__global__ __launch_bounds__(256) void embs_partial_kernel(
    const float* __restrict__ betas, // [10,2048]
    const float* __restrict__ H2,    // [2048,1024]
    float* __restrict__ embs)        // [10,1024]
{
    const int t = blockIdx.y;
    const int colc = blockIdx.x & 3;
    const int nc = blockIdx.x >> 2;
    const int col = colc*256 + threadIdx.x;
    const int n0 = nc*256;
    float acc = 0.0f;
    for (int n = n0; n < n0+256; ++n)
        acc = fmaf(betas[t*2048+n], H2[(size_t)n*1024+col], acc);
    atomicAdd(&embs[t*1024+col], acc);
}

// ---------------- global attention + classifier + A ----------------
__global__ __launch_bounds__(256) void final_kernel(
    const float* __restrict__ embs,  // [10,1024]
    const float* __restrict__ betas, // [10,2048]
    const float* __restrict__ gw1, const float* __restrict__ gb1,
    const float* __restrict__ gw2, const float* __restrict__ gb2,
    const float* __restrict__ cw,  const float* __restrict__ cb,
    float* __restrict__ out)         // [2051] = Y_prob[2], Y_hat[1], A[2048]
{
    __shared__ float sg[10];
    __shared__ float gam[10];
    __shared__ float sM[1024];
    __shared__ float red[256];
    __shared__ float v0s;
    const int tid = threadIdx.x;
    if (tid < 10) sg[tid] = 0.0f;
    __syncthreads();
    // g[t] = sum_k tanh(embs[t].gw1[k] + gb1[k]) * gw2[k]   (+ gb2 later)
    for (int task = tid; task < 1280; task += 256) {
        const int t = task >> 7, k = task & 127;
        const float* e = embs + t*1024;
        const float* w = gw1 + k*1024;
        float s = gb1[k];
        for (int q = 0; q < 1024; ++q) s = fmaf(e[q], w[q], s);
        atomicAdd(&sg[t], tanhf(s)*gw2[k]);
    }
    __syncthreads();
    if (tid == 0) {
        float mx = -1e30f;
        for (int t = 0; t < 10; ++t) mx = fmaxf(mx, sg[t] + gb2[0]);
        float sum = 0.0f;
        for (int t = 0; t < 10; ++t) { gam[t] = expf(sg[t] + gb2[0] - mx); sum += gam[t]; }
        for (int t = 0; t < 10; ++t) gam[t] /= sum;
    }
    __syncthreads();
    for (int col = tid; col < 1024; col += 256) {
        float m = 0.0f;
        for (int t = 0; t < 10; ++t) m = fmaf(gam[t], embs[t*1024+col], m);
        sM[col] = m;
    }
    for (int n = tid; n < 2048; n += 256) {
        float a = 0.0f;
        for (int t = 0; t < 10; ++t) a = fmaf(gam[t], betas[t*2048+n], a);
        out[3+n] = a;
    }
    __syncthreads();
    float s0 = 0.0f, s1 = 0.0f;
    for (int q = tid; q < 1024; q += 256) {
        s0 = fmaf(sM[q], cw[q], s0);
        s1 = fmaf(sM[q], cw[1024+q], s1);
    }
    red[tid] = s0; __syncthreads();
    for (int s = 128; s; s >>= 1) { if (tid < s) red[tid] += red[tid+s]; __syncthreads(); }
    if (tid == 0) v0s = red[0];
    __syncthreads();
    red[tid] = s1; __syncthreads();
    for (int s = 128; s; s >>= 1) { if (tid < s) red[tid] += red[tid+s]; __syncthreads(); }
    if (tid == 0) {
        const float l0 = v0s + cb[0], l1 = red[0] + cb[1];
        const float p0 = 1.0f/(1.0f+expf(-l0));
        const float p1 = 1.0f/(1.0f+expf(-l1));
        out[0] = p0; out[1] = p1;
        out[2] = (p1 > p0) ? 1.0f : 0.0f;   // argmax (first max on tie -> 0)
    }
}

extern "C" void kernel_launch(void* const* d_in, const int* in_sizes, int n_in,
                              void* d_out, int out_size, void* d_ws, size_t ws_size,
                              hipStream_t stream)
{
    const float* x        = (const float*)d_in[0];
    // d_in[1] = positions (implicit: 32x64 grid, derived from index)
    const float* conv1_w  = (const float*)d_in[2];
    const float* conv1_b  = (const float*)d_in[3];
    const float* conv2_w  = (const float*)d_in[4];
    const float* conv2_b  = (const float*)d_in[5];
    const float* fc1_w    = (const float*)d_in[6];
    const float* fc1_b    = (const float*)d_in[7];
    const float* fc2_w    = (const float*)d_in[8];
    const float* fc2_b    = (const float*)d_in[9];
    const float* nbr_w    = (const float*)d_in[10];
    const float* nbr_b    = (const float*)d_in[11];
    const float* templ    = (const float*)d_in[12];
    const float* proto_w  = (const float*)d_in[13];
    const float* proto_b  = (const float*)d_in[14];
    const float* glob_w1  = (const float*)d_in[15];
    const float* glob_b1  = (const float*)d_in[16];
    const float* glob_w2  = (const float*)d_in[17];
    const float* glob_b2  = (const float*)d_in[18];
    const float* cls_w    = (const float*)d_in[19];
    const float* cls_b    = (const float*)d_in[20];
    float* out = (float*)d_out;

    float* ws = (float*)d_ws;
    float* Hf    = ws; ws += (size_t)2048*1728;
    float* Hfc1  = ws; ws += (size_t)2048*512;
    float* H     = ws; ws += (size_t)2048*512;
    float* An    = ws; ws += (size_t)2048*512;
    float* H2    = ws; ws += (size_t)2048*1024;
    float* P     = ws; ws += (size_t)2048*1024;
    float* S     = ws; ws += (size_t)2048*10;
    float* betas = ws; ws += (size_t)10*2048;
    float* embs  = ws; ws += (size_t)10*1024;

    conv_fused_kernel<<<2048, 256, 0, stream>>>(x, conv1_w, conv1_b, conv2_w, conv2_b, Hf);
    gemm_bias_act<1><<<dim3(8, 32), 256, 0, stream>>>(Hf,   fc1_w,   fc1_b,   Hfc1, 512, 1728);
    gemm_bias_act<1><<<dim3(8, 32), 256, 0, stream>>>(Hfc1, fc2_w,   fc2_b,   H,    512, 512);
    gemm_bias_act<2><<<dim3(8, 32), 256, 0, stream>>>(H,    nbr_w,   nbr_b,   An,   512, 512);
    nbr_attn_kernel<<<2048, 64, 0, stream>>>(H, An, H2);
    gemm_bias_act<2><<<dim3(16, 32), 256, 0, stream>>>(H2,  proto_w, proto_b, P,    1024, 1024);
    template_scores_kernel<<<2048, 64, 0, stream>>>(P, templ, S);
    beta_softmax_kernel<<<10, 256, 0, stream>>>(S, betas);
    zero_kernel<<<40, 256, 0, stream>>>(embs, 10240);
    embs_partial_kernel<<<dim3(32, 10), 256, 0, stream>>>(betas, H2, embs);
    final_kernel<<<1, 256, 0, stream>>>(embs, betas, glob_w1, glob_b1, glob_w2, glob_b2,
                                        cls_w, cls_b, out);
}

// Round 2
// 737.065 us; speedup vs baseline: 1.2562x; 1.2562x over previous
//
#include <hip/hip_runtime.h>
#include <hip/hip_bf16.h>
#include <math.h>

// ---------------------------------------------------------------------------
// MAMIL round 2: conv_fused restructured for zero LDS bank conflicts.
//   - spatial-major/channel-inner thread mapping -> activation reads are
//     wave-broadcast, weight reads are lane-stride-1
//   - conv2 inner loop: ds_read_b128 over 4 input channels, 2x2 pool-window
//     register blocking, coalesced transposed weights from L2
// Everything downstream unchanged from round 1 (fp32, passed at 1.9e-6).
// ---------------------------------------------------------------------------

// ---------------- transpose conv2 weights: w2t[(ic*9+q)*48 + oc] ----------
__global__ __launch_bounds__(256) void transpose_w2_kernel(
    const float* __restrict__ w2,  // [48,36,9]
    float* __restrict__ w2t)       // [324,48]
{
    const int i = blockIdx.x*256 + threadIdx.x;
    if (i < 15552) {
        const int k = i / 48, oc = i % 48;
        w2t[i] = w2[oc*324 + k];
    }
}

// ---------------- fused conv1+relu+pool -> conv2+relu+pool ----------------
__global__ __launch_bounds__(256) void conv_fused_kernel(
    const float* __restrict__ x,   // [2048,32,32]
    const float* __restrict__ w1,  // [36,16]
    const float* __restrict__ b1,  // [36]
    const float* __restrict__ w2t, // [324,48] transposed
    const float* __restrict__ b2,  // [48]
    float* __restrict__ out)       // [2048,1728]  (layout oc*36 + r2)
{
    __shared__ float sx[1024];
    __shared__ float sw1t[576];    // [16][36]: sw1t[k*36+c] = w1[c*16+k]
    __shared__ float sh1[7056];    // [196][36]: pos-major, channel-inner
    const int n = blockIdx.x;
    const int tid = threadIdx.x;
    for (int i = tid; i < 1024; i += 256) sx[i] = x[(size_t)n*1024 + i];
    for (int i = tid; i < 576;  i += 256) {
        const int k = i / 36, c = i % 36;
        sw1t[i] = w1[c*16 + k];
    }
    __syncthreads();

    // conv1 (1->36, 4x4, VALID 32->29) + relu + 2x2 pool -> [196][36]
    for (int o = tid; o < 7056; o += 256) {
        const int c = o % 36;
        const int pos = o / 36;
        const int py = pos / 14, px = pos % 14;
        float wreg[16];
        #pragma unroll
        for (int k = 0; k < 16; ++k) wreg[k] = sw1t[k*36 + c];
        const int oy0 = 2*py, ox0 = 2*px;
        float win[25];
        #pragma unroll
        for (int r = 0; r < 5; ++r)
        #pragma unroll
        for (int cc = 0; cc < 5; ++cc)
            win[r*5+cc] = sx[(oy0+r)*32 + ox0 + cc];
        const float bb = b1[c];
        float m = -1e30f;
        #pragma unroll
        for (int dy = 0; dy < 2; ++dy)
        #pragma unroll
        for (int dx = 0; dx < 2; ++dx) {
            float s = bb;
            #pragma unroll
            for (int ky = 0; ky < 4; ++ky)
            #pragma unroll
            for (int kx = 0; kx < 4; ++kx)
                s = fmaf(win[(dy+ky)*5 + dx+kx], wreg[ky*4+kx], s);
            m = fmaxf(m, s);
        }
        sh1[pos*36 + c] = fmaxf(m, 0.0f);
    }
    __syncthreads();

    // conv2 (36->48, 3x3, VALID 14->12) + relu + 2x2 pool -> 6x6, 48 ch
    for (int o2 = tid; o2 < 1728; o2 += 256) {
        const int oc = o2 % 48;
        const int r2 = o2 / 48;
        const int py2 = r2 / 6, px2 = r2 % 6;
        const int pbase = (2*py2)*14 + 2*px2;
        const float bb = b2[oc];
        float s00 = bb, s01 = bb, s10 = bb, s11 = bb;
        for (int c4 = 0; c4 < 36; c4 += 4) {
            float4 hv[16];
            #pragma unroll
            for (int wy = 0; wy < 4; ++wy)
            #pragma unroll
            for (int wx = 0; wx < 4; ++wx)
                hv[wy*4+wx] = *(const float4*)&sh1[(pbase + wy*14 + wx)*36 + c4];
            #define ICC_BLOCK(ICC, COMP)                                        \
            {                                                                   \
                float wv[9];                                                    \
                _Pragma("unroll")                                               \
                for (int q = 0; q < 9; ++q)                                     \
                    wv[q] = w2t[((c4+ICC)*9 + q)*48 + oc];                      \
                _Pragma("unroll")                                               \
                for (int ky = 0; ky < 3; ++ky) {                                \
                    _Pragma("unroll")                                           \
                    for (int kx = 0; kx < 3; ++kx) {                            \
                        const float w = wv[ky*3+kx];                            \
                        s00 = fmaf(hv[(ky  )*4 + kx    ].COMP, w, s00);         \
                        s01 = fmaf(hv[(ky  )*4 + kx + 1].COMP, w, s01);         \
                        s10 = fmaf(hv[(ky+1)*4 + kx    ].COMP, w, s10);         \
                        s11 = fmaf(hv[(ky+1)*4 + kx + 1].COMP, w, s11);         \
                    }                                                           \
                }                                                               \
            }
            ICC_BLOCK(0, x)
            ICC_BLOCK(1, y)
            ICC_BLOCK(2, z)
            ICC_BLOCK(3, w)
            #undef ICC_BLOCK
        }
        const float m = fmaxf(fmaxf(s00, s01), fmaxf(s10, s11));
        out[(size_t)n*1728 + oc*36 + r2] = fmaxf(m, 0.0f);
    }
}

// ---------------- C[M,N] = act(A[M,K] @ W[N,K]^T + bias) ----------------
// ACT: 0 = none, 1 = relu, 2 = tanh.  Requires M%64==0, N%64==0, K%16==0.
template<int ACT>
__global__ __launch_bounds__(256) void gemm_bias_act(
    const float* __restrict__ A, const float* __restrict__ W,
    const float* __restrict__ bias, float* __restrict__ C,
    const int N, const int K)
{
    __shared__ float sA[16][68];
    __shared__ float sB[16][68];
    const int bn = blockIdx.x, bm = blockIdx.y;
    const int tid = threadIdx.x;
    const int tx = tid & 15, ty = tid >> 4;
    const int lr = tid >> 2;            // 0..63
    const int lk = (tid & 3) << 2;      // 0,4,8,12
    const float* Ap = A + (size_t)(bm*64 + lr)*K + lk;
    const float* Wp = W + (size_t)(bn*64 + lr)*K + lk;
    float acc[4][4] = {};
    for (int k0 = 0; k0 < K; k0 += 16) {
        const float4 a4 = *(const float4*)(Ap + k0);
        const float4 w4 = *(const float4*)(Wp + k0);
        sA[lk+0][lr] = a4.x; sA[lk+1][lr] = a4.y; sA[lk+2][lr] = a4.z; sA[lk+3][lr] = a4.w;
        sB[lk+0][lr] = w4.x; sB[lk+1][lr] = w4.y; sB[lk+2][lr] = w4.z; sB[lk+3][lr] = w4.w;
        __syncthreads();
        #pragma unroll
        for (int kk = 0; kk < 16; ++kk) {
            float av[4], wv[4];
            #pragma unroll
            for (int i = 0; i < 4; ++i) av[i] = sA[kk][ty*4+i];
            #pragma unroll
            for (int j = 0; j < 4; ++j) wv[j] = sB[kk][tx*4+j];
            #pragma unroll
            for (int i = 0; i < 4; ++i)
            #pragma unroll
            for (int j = 0; j < 4; ++j)
                acc[i][j] = fmaf(av[i], wv[j], acc[i][j]);
        }
        __syncthreads();
    }
    const int row = bm*64 + ty*4;
    const int col = bn*64 + tx*4;
    #pragma unroll
    for (int i = 0; i < 4; ++i)
    #pragma unroll
    for (int j = 0; j < 4; ++j) {
        float v = acc[i][j] + bias[col+j];
        if (ACT == 1) v = fmaxf(v, 0.0f);
        if (ACT == 2) v = tanhf(v);
        C[(size_t)(row+i)*N + col+j] = v;
    }
}

// ---------------- sparse neighborhood attention ----------------
__global__ __launch_bounds__(64) void nbr_attn_kernel(
    const float* __restrict__ H,   // [2048,512]
    const float* __restrict__ An,  // [2048,512]
    float* __restrict__ H2)        // [2048,1024] = [H | Hn]
{
    const int i = blockIdx.x;
    const int lane = threadIdx.x;
    const int r = i >> 6, c = i & 63;
    int nbr[8]; int nn = 0;
    for (int dr = -1; dr <= 1; ++dr)
    for (int dc = -1; dc <= 1; ++dc) {
        if (dr == 0 && dc == 0) continue;
        const int rr = r + dr, cc = c + dc;
        if (rr >= 0 && rr < 32 && cc >= 0 && cc < 64) nbr[nn++] = rr*64 + cc;
    }
    float hi[8];
    #pragma unroll
    for (int q = 0; q < 8; ++q) hi[q] = H[(size_t)i*512 + q*64 + lane];
    float logits[8];
    for (int j = 0; j < nn; ++j) {
        const float* an = An + (size_t)nbr[j]*512;
        float s = 0.0f;
        #pragma unroll
        for (int q = 0; q < 8; ++q) s = fmaf(hi[q], an[q*64+lane], s);
        for (int off = 32; off; off >>= 1) s += __shfl_xor(s, off);
        logits[j] = s;
    }
    float mx = -1e30f;
    for (int j = 0; j < nn; ++j) mx = fmaxf(mx, logits[j]);
    float sum = 0.0f; float al[8];
    for (int j = 0; j < nn; ++j) { al[j] = expf(logits[j]-mx); sum += al[j]; }
    const float inv = 1.0f/sum;
    float hn[8] = {};
    for (int j = 0; j < nn; ++j) {
        const float* hj = H + (size_t)nbr[j]*512;
        const float a = al[j]*inv;
        #pragma unroll
        for (int q = 0; q < 8; ++q) hn[q] = fmaf(a, hj[q*64+lane], hn[q]);
    }
    #pragma unroll
    for (int q = 0; q < 8; ++q) {
        H2[(size_t)i*1024 + q*64 + lane]       = hi[q];
        H2[(size_t)i*1024 + 512 + q*64 + lane] = hn[q];
    }
}

// ---------------- S[n,t] = P[n,:] . templates[t,:] ----------------
__global__ __launch_bounds__(64) void template_scores_kernel(
    const float* __restrict__ P,   // [2048,1024]
    const float* __restrict__ Tm,  // [10,1024]
    float* __restrict__ S)         // [2048,10]
{
    const int n = blockIdx.x;
    const int lane = threadIdx.x;
    float p[16];
    #pragma unroll
    for (int q = 0; q < 16; ++q) p[q] = P[(size_t)n*1024 + q*64 + lane];
    for (int t = 0; t < 10; ++t) {
        const float* tm = Tm + t*1024;
        float s = 0.0f;
        #pragma unroll
        for (int q = 0; q < 16; ++q) s = fmaf(p[q], tm[q*64+lane], s);
        for (int off = 32; off; off >>= 1) s += __shfl_xor(s, off);
        if (lane == 0) S[n*10 + t] = s;
    }
}

// ---------------- betas[t,:] = softmax_n(S[:,t]) ----------------
__global__ __launch_bounds__(256) void beta_softmax_kernel(
    const float* __restrict__ S, float* __restrict__ betas)
{
    const int t = blockIdx.x;
    __shared__ float red[256];
    const int tid = threadIdx.x;
    float mx = -1e30f;
    for (int n = tid; n < 2048; n += 256) mx = fmaxf(mx, S[n*10+t]);
    red[tid] = mx; __syncthreads();
    for (int s = 128; s; s >>= 1) { if (tid < s) red[tid] = fmaxf(red[tid], red[tid+s]); __syncthreads(); }
    mx = red[0]; __syncthreads();
    float sum = 0.0f;
    for (int n = tid; n < 2048; n += 256) sum += expf(S[n*10+t]-mx);
    red[tid] = sum; __syncthreads();
    for (int s = 128; s; s >>= 1) { if (tid < s) red[tid] += red[tid+s]; __syncthreads(); }
    const float inv = 1.0f/red[0];
    for (int n = tid; n < 2048; n += 256) betas[t*2048+n] = expf(S[n*10+t]-mx)*inv;
}

__global__ __launch_bounds__(256) void zero_kernel(float* p, int n)
{
    const int i = blockIdx.x*256 + threadIdx.x;
    if (i < n) p[i] = 0.0f;
}

// ---------------- embs[t,:] += betas[t,chunk] @ H2[chunk,:] ----------------
__global__ __launch_bounds__(256) void embs_partial_kernel(
    const float* __restrict__ betas, // [10,2048]
    const float* __restrict__ H2,    // [2048,1024]
    float* __restrict__ embs)        // [10,1024]
{
    const int t = blockIdx.y;
    const int colc = blockIdx.x & 3;
    const int nc = blockIdx.x >> 2;
    const int col = colc*256 + threadIdx.x;
    const int n0 = nc*256;
    float acc = 0.0f;
    for (int n = n0; n < n0+256; ++n)
        acc = fmaf(betas[t*2048+n], H2[(size_t)n*1024+col], acc);
    atomicAdd(&embs[t*1024+col], acc);
}

// ---------------- global attention + classifier + A ----------------
__global__ __launch_bounds__(256) void final_kernel(
    const float* __restrict__ embs,  // [10,1024]
    const float* __restrict__ betas, // [10,2048]
    const float* __restrict__ gw1, const float* __restrict__ gb1,
    const float* __restrict__ gw2, const float* __restrict__ gb2,
    const float* __restrict__ cw,  const float* __restrict__ cb,
    float* __restrict__ out)         // [2051] = Y_prob[2], Y_hat[1], A[2048]
{
    __shared__ float sg[10];
    __shared__ float gam[10];
    __shared__ float sM[1024];
    __shared__ float red[256];
    __shared__ float v0s;
    const int tid = threadIdx.x;
    if (tid < 10) sg[tid] = 0.0f;
    __syncthreads();
    for (int task = tid; task < 1280; task += 256) {
        const int t = task >> 7, k = task & 127;
        const float* e = embs + t*1024;
        const float* w = gw1 + k*1024;
        float s = gb1[k];
        for (int q = 0; q < 1024; ++q) s = fmaf(e[q], w[q], s);
        atomicAdd(&sg[t], tanhf(s)*gw2[k]);
    }
    __syncthreads();
    if (tid == 0) {
        float mx = -1e30f;
        for (int t = 0; t < 10; ++t) mx = fmaxf(mx, sg[t] + gb2[0]);
        float sum = 0.0f;
        for (int t = 0; t < 10; ++t) { gam[t] = expf(sg[t] + gb2[0] - mx); sum += gam[t]; }
        for (int t = 0; t < 10; ++t) gam[t] /= sum;
    }
    __syncthreads();
    for (int col = tid; col < 1024; col += 256) {
        float m = 0.0f;
        for (int t = 0; t < 10; ++t) m = fmaf(gam[t], embs[t*1024+col], m);
        sM[col] = m;
    }
    for (int n = tid; n < 2048; n += 256) {
        float a = 0.0f;
        for (int t = 0; t < 10; ++t) a = fmaf(gam[t], betas[t*2048+n], a);
        out[3+n] = a;
    }
    __syncthreads();
    float s0 = 0.0f, s1 = 0.0f;
    for (int q = tid; q < 1024; q += 256) {
        s0 = fmaf(sM[q], cw[q], s0);
        s1 = fmaf(sM[q], cw[1024+q], s1);
    }
    red[tid] = s0; __syncthreads();
    for (int s = 128; s; s >>= 1) { if (tid < s) red[tid] += red[tid+s]; __syncthreads(); }
    if (tid == 0) v0s = red[0];
    __syncthreads();
    red[tid] = s1; __syncthreads();
    for (int s = 128; s; s >>= 1) { if (tid < s) red[tid] += red[tid+s]; __syncthreads(); }
    if (tid == 0) {
        const float l0 = v0s + cb[0], l1 = red[0] + cb[1];
        const float p0 = 1.0f/(1.0f+expf(-l0));
        const float p1 = 1.0f/(1.0f+expf(-l1));
        out[0] = p0; out[1] = p1;
        out[2] = (p1 > p0) ? 1.0f : 0.0f;
    }
}

extern "C" void kernel_launch(void* const* d_in, const int* in_sizes, int n_in,
                              void* d_out, int out_size, void* d_ws, size_t ws_size,
                              hipStream_t stream)
{
    const float* x        = (const float*)d_in[0];
    const float* conv1_w  = (const float*)d_in[2];
    const float* conv1_b  = (const float*)d_in[3];
    const float* conv2_w  = (const float*)d_in[4];
    const float* conv2_b  = (const float*)d_in[5];
    const float* fc1_w    = (const float*)d_in[6];
    const float* fc1_b    = (const float*)d_in[7];
    const float* fc2_w    = (const float*)d_in[8];
    const float* fc2_b    = (const float*)d_in[9];
    const float* nbr_w    = (const float*)d_in[10];
    const float* nbr_b    = (const float*)d_in[11];
    const float* templ    = (const float*)d_in[12];
    const float* proto_w  = (const float*)d_in[13];
    const float* proto_b  = (const float*)d_in[14];
    const float* glob_w1  = (const float*)d_in[15];
    const float* glob_b1  = (const float*)d_in[16];
    const float* glob_w2  = (const float*)d_in[17];
    const float* glob_b2  = (const float*)d_in[18];
    const float* cls_w    = (const float*)d_in[19];
    const float* cls_b    = (const float*)d_in[20];
    float* out = (float*)d_out;

    float* ws = (float*)d_ws;
    float* Hf    = ws; ws += (size_t)2048*1728;
    float* Hfc1  = ws; ws += (size_t)2048*512;
    float* H     = ws; ws += (size_t)2048*512;
    float* An    = ws; ws += (size_t)2048*512;
    float* H2    = ws; ws += (size_t)2048*1024;
    float* P     = ws; ws += (size_t)2048*1024;
    float* S     = ws; ws += (size_t)2048*10;
    float* betas = ws; ws += (size_t)10*2048;
    float* embs  = ws; ws += (size_t)10*1024;
    float* w2t   = ws; ws += (size_t)324*48;

    transpose_w2_kernel<<<61, 256, 0, stream>>>(conv2_w, w2t);
    conv_fused_kernel<<<2048, 256, 0, stream>>>(x, conv1_w, conv1_b, w2t, conv2_b, Hf);
    gemm_bias_act<1><<<dim3(8, 32), 256, 0, stream>>>(Hf,   fc1_w,   fc1_b,   Hfc1, 512, 1728);
    gemm_bias_act<1><<<dim3(8, 32), 256, 0, stream>>>(Hfc1, fc2_w,   fc2_b,   H,    512, 512);
    gemm_bias_act<2><<<dim3(8, 32), 256, 0, stream>>>(H,    nbr_w,   nbr_b,   An,   512, 512);
    nbr_attn_kernel<<<2048, 64, 0, stream>>>(H, An, H2);
    gemm_bias_act<2><<<dim3(16, 32), 256, 0, stream>>>(H2,  proto_w, proto_b, P,    1024, 1024);
    template_scores_kernel<<<2048, 64, 0, stream>>>(P, templ, S);
    beta_softmax_kernel<<<10, 256, 0, stream>>>(S, betas);
    zero_kernel<<<40, 256, 0, stream>>>(embs, 10240);
    embs_partial_kernel<<<dim3(32, 10), 256, 0, stream>>>(betas, H2, embs);
    final_kernel<<<1, 256, 0, stream>>>(embs, betas, glob_w1, glob_b1, glob_w2, glob_b2,
                                        cls_w, cls_b, out);
}

// Round 3
// 341.631 us; speedup vs baseline: 2.7102x; 2.1575x over previous
//
#include <hip/hip_runtime.h>
#include <hip/hip_bf16.h>
#include <math.h>

// ---------------------------------------------------------------------------
// MAMIL round 3: MFMA everywhere.
//  - conv1+pool+conv2+pool as per-instance implicit GEMM on mfma_f32_16x16x32_bf16
//    (im2col ordered so pooling = max over one lane's 4 acc regs)
//  - fc1/fc2/nbr/proto as split-bf16 (hi+lo Markidis) MFMA GEMM for fp32-like
//    accuracy (beta-softmax logits are sensitive to ~0.05 perturbations)
//  - XOR-swizzled LDS tiles for conflict-free ds_read_b128 fragment loads
//  - final attention split: per-template glob_g blocks + tiny final2
// ---------------------------------------------------------------------------

typedef short short8 __attribute__((ext_vector_type(8)));
typedef float f32x4  __attribute__((ext_vector_type(4)));

__device__ inline short f2bf(float f) {
    unsigned u = __builtin_bit_cast(unsigned, f);
    u += 0x7fff + ((u >> 16) & 1);
    return (short)(u >> 16);
}
__device__ inline float bf2f(short h) {
    unsigned u = ((unsigned)(unsigned short)h) << 16;
    return __builtin_bit_cast(float, u);
}
__device__ inline f32x4 mfma16(short8 a, short8 b, f32x4 c) {
    return __builtin_amdgcn_mfma_f32_16x16x32_bf16(a, b, c, 0, 0, 0);
}

// ---------------- weight prep ----------------
__global__ __launch_bounds__(256) void split_cast_kernel(
    const float* __restrict__ s, short* __restrict__ hi, short* __restrict__ lo, int n)
{
    int i = blockIdx.x*256 + threadIdx.x;
    if (i < n) {
        float f = s[i];
        short h = f2bf(f);
        hi[i] = h;
        lo[i] = f2bf(f - bf2f(h));
    }
}

__global__ __launch_bounds__(64) void prep_w1m_kernel(
    const float* __restrict__ w1, short* __restrict__ w1m)   // [48][32]
{
    int i = blockIdx.x*64 + threadIdx.x;
    if (i < 1536) {
        int c = i >> 5, k = i & 31;
        w1m[i] = (c < 36 && k < 16) ? f2bf(w1[c*16 + k]) : (short)0;
    }
}

__global__ __launch_bounds__(256) void prep_w2m_kernel(
    const float* __restrict__ w2, short* __restrict__ w2m)   // [48][576], k=tap*64+ic
{
    int i = blockIdx.x*256 + threadIdx.x;
    if (i < 27648) {
        int oc = i / 576, r = i % 576, tap = r >> 6, c = r & 63;
        w2m[i] = (c < 36) ? f2bf(w2[oc*324 + c*9 + tap]) : (short)0;
    }
}

// ---------------- fused conv1+pool -> conv2+pool (MFMA) ----------------
// im2col row order p' = pooledpos*4 + (dy*2+dx): each 16-row M-tile = 4 pooled
// positions; D-frag row = (lane>>4)*4+i, so pool = max over the 4 acc regs.
__global__ __launch_bounds__(256) void conv_mfma_kernel(
    const float* __restrict__ x,     // [2048][1024]
    const short* __restrict__ w1m,   // [48][32]
    const float* __restrict__ b1,    // [36]
    const short* __restrict__ w2m,   // [48][576]
    const float* __restrict__ b2,    // [48]
    short* __restrict__ Hfhi, short* __restrict__ Hflo)  // [2048][1728], oc*36+r2
{
    __shared__ __align__(16) short win[400*32];  // im2col half-batch, swz ((row&3)<<4)
    __shared__ __align__(16) short sh1[196*64];  // [h1row][64] ic-padded, swz ((row&7)<<4)
    const int n = blockIdx.x, tid = threadIdx.x;
    const int l = tid & 63, w = tid >> 6, g = l >> 4, fr = l & 15;

    // zero sh1 (padding cols must be 0)
    {
        short8 z = {};
        for (int i = tid; i < 196*64/8; i += 256) *(short8*)&sh1[i*8] = z;
    }
    // conv1 B-frags from global (L2), cached in regs
    short8 bw1[3];
    #pragma unroll
    for (int nt = 0; nt < 3; ++nt)
        bw1[nt] = *(const short8*)(w1m + (nt*16 + fr)*32 + g*8);

    // ---- conv1 in two phases (LDS budget): rows [0,400) then [400,784) ----
    for (int ph = 0; ph < 2; ++ph) {
        const int rowbase = ph ? 400 : 0;
        const int cnt     = ph ? 384 : 400;
        __syncthreads();   // prior phase reads done (and sh1 zeros visible)
        for (int pl = tid; pl < cnt; pl += 256) {
            const int pp = rowbase + pl;
            const int q = pp >> 2, dd = pp & 3;
            const int py = q / 14, px = q % 14;
            const int iy0 = 2*py + (dd >> 1), ix0 = 2*px + (dd & 1);
            const float* xs = x + (size_t)n*1024 + iy0*32 + ix0;
            short v[16];
            #pragma unroll
            for (int ky = 0; ky < 4; ++ky)
                #pragma unroll
                for (int kx = 0; kx < 4; ++kx)
                    v[ky*4+kx] = f2bf(xs[ky*32 + kx]);
            const int sw = (pl & 3) << 4;
            char* base = (char*)win + pl*64;
            short8 z = {};
            *(short8*)(base + ( 0 ^ sw)) = *(short8*)&v[0];
            *(short8*)(base + (16 ^ sw)) = *(short8*)&v[8];
            *(short8*)(base + (32 ^ sw)) = z;
            *(short8*)(base + (48 ^ sw)) = z;
        }
        __syncthreads();
        const int mt0 = ph ? 25 : 0, mt1 = ph ? 49 : 25;
        for (int mt = mt0 + w; mt < mt1; mt += 4) {
            const int rl = mt*16 - rowbase + fr;
            short8 af = *(const short8*)((char*)win + ((rl*64 + g*16) ^ ((rl & 3) << 4)));
            f32x4 acc[3] = {};
            #pragma unroll
            for (int nt = 0; nt < 3; ++nt) acc[nt] = mfma16(af, bw1[nt], acc[nt]);
            const int q1 = mt*4 + g;          // pooled pos 0..195
            #pragma unroll
            for (int nt = 0; nt < 3; ++nt) {
                const int c = nt*16 + fr;
                if (c < 36) {
                    float m = fmaxf(fmaxf(acc[nt][0], acc[nt][1]),
                                    fmaxf(acc[nt][2], acc[nt][3]));
                    m = fmaxf(m + b1[c], 0.0f);
                    *(short*)((char*)sh1 + ((q1*128 + c*2) ^ ((q1 & 7) << 4))) = f2bf(m);
                }
            }
        }
    }
    __syncthreads();   // sh1 complete

    // ---- conv2: M=144 (p' = pooled*4+quad), N=48, K=18 steps of 32 ----
    for (int mt = w; mt < 9; mt += 4) {
        const int pp = mt*16 + fr;          // A-row this lane reads
        const int q2 = pp >> 2, dd = pp & 3;
        const int oy = 2*(q2/6) + (dd >> 1), ox = 2*(q2%6) + (dd & 1);
        short8 afr[18];
        #pragma unroll
        for (int tap = 0; tap < 9; ++tap) {
            const int ky = tap/3, kx = tap%3;
            const int hr = (oy+ky)*14 + ox + kx;
            const int sw = (hr & 7) << 4;
            char* rb = (char*)sh1 + hr*128;
            afr[tap*2+0] = *(short8*)(rb + ((     g*16) ^ sw));
            afr[tap*2+1] = *(short8*)(rb + ((64 + g*16) ^ sw));
        }
        #pragma unroll
        for (int nt = 0; nt < 3; ++nt) {
            const short* wb = w2m + (size_t)(nt*16 + fr)*576 + g*8;
            f32x4 acc = {};
            #pragma unroll
            for (int ks = 0; ks < 18; ++ks)
                acc = mfma16(afr[ks], *(const short8*)(wb + ks*32), acc);
            const int oc = nt*16 + fr;
            float m = fmaxf(fmaxf(acc[0], acc[1]), fmaxf(acc[2], acc[3]));
            m = fmaxf(m + b2[oc], 0.0f);
            const size_t idx = (size_t)n*1728 + oc*36 + (mt*4 + g);
            const short hh = f2bf(m);
            Hfhi[idx] = hh;
            Hflo[idx] = f2bf(m - bf2f(hh));
        }
    }
}

// ---------------- split-bf16 MFMA GEMM: C = act(A @ W^T + bias) ----------------
// A,W given as bf16 hi/lo planes [M][K],[N][K]. M%64==0, N%64==0, K%64==0.
template<int ACT, int OUTF32, int OUTBF>
__global__ __launch_bounds__(256) void gemm_split_kernel(
    const short* __restrict__ Ahi, const short* __restrict__ Alo,
    const short* __restrict__ Whi, const short* __restrict__ Wlo,
    const float* __restrict__ bias,
    float* __restrict__ Cf, short* __restrict__ Chi, short* __restrict__ Clo,
    const int N, const int K)
{
    __shared__ __align__(16) short sA[2][4096];   // [hi/lo][row*64+k], swz ((row&7)<<4)
    __shared__ __align__(16) short sB[2][4096];
    const int bn = blockIdx.x, bm = blockIdx.y;
    const int tid = threadIdx.x, l = tid & 63, w = tid >> 6, g = l >> 4, fr = l & 15;
    const int srow = tid >> 2, kc = (tid & 3) << 4;
    const size_t aoff = (size_t)(bm*64 + srow)*K + kc;
    const size_t boff = (size_t)(bn*64 + srow)*K + kc;
    const int swb = (srow & 7) << 4;
    const int wbase = srow*128 + kc*2;
    f32x4 acc[4] = {};
    for (int k0 = 0; k0 < K; k0 += 64) {
        const short8 a0 = *(const short8*)(Ahi + aoff + k0);
        const short8 a1 = *(const short8*)(Ahi + aoff + k0 + 8);
        const short8 a2 = *(const short8*)(Alo + aoff + k0);
        const short8 a3 = *(const short8*)(Alo + aoff + k0 + 8);
        const short8 b0 = *(const short8*)(Whi + boff + k0);
        const short8 b1 = *(const short8*)(Whi + boff + k0 + 8);
        const short8 b2 = *(const short8*)(Wlo + boff + k0);
        const short8 b3 = *(const short8*)(Wlo + boff + k0 + 8);
        __syncthreads();
        *(short8*)((char*)&sA[0][0] + ((wbase     ) ^ swb)) = a0;
        *(short8*)((char*)&sA[0][0] + ((wbase + 16) ^ swb)) = a1;
        *(short8*)((char*)&sA[1][0] + ((wbase     ) ^ swb)) = a2;
        *(short8*)((char*)&sA[1][0] + ((wbase + 16) ^ swb)) = a3;
        *(short8*)((char*)&sB[0][0] + ((wbase     ) ^ swb)) = b0;
        *(short8*)((char*)&sB[0][0] + ((wbase + 16) ^ swb)) = b1;
        *(short8*)((char*)&sB[1][0] + ((wbase     ) ^ swb)) = b2;
        *(short8*)((char*)&sB[1][0] + ((wbase + 16) ^ swb)) = b3;
        __syncthreads();
        const int ar = w*16 + fr, asw = (ar & 7) << 4;
        const short8 ah0 = *(const short8*)((char*)&sA[0][0] + ((ar*128      + g*16) ^ asw));
        const short8 ah1 = *(const short8*)((char*)&sA[0][0] + ((ar*128 + 64 + g*16) ^ asw));
        const short8 al0 = *(const short8*)((char*)&sA[1][0] + ((ar*128      + g*16) ^ asw));
        const short8 al1 = *(const short8*)((char*)&sA[1][0] + ((ar*128 + 64 + g*16) ^ asw));
        #pragma unroll
        for (int nt = 0; nt < 4; ++nt) {
            const int br = nt*16 + fr, bsw = (br & 7) << 4;
            const short8 bh0 = *(const short8*)((char*)&sB[0][0] + ((br*128      + g*16) ^ bsw));
            const short8 bh1 = *(const short8*)((char*)&sB[0][0] + ((br*128 + 64 + g*16) ^ bsw));
            const short8 bl0 = *(const short8*)((char*)&sB[1][0] + ((br*128      + g*16) ^ bsw));
            const short8 bl1 = *(const short8*)((char*)&sB[1][0] + ((br*128 + 64 + g*16) ^ bsw));
            acc[nt] = mfma16(ah0, bh0, acc[nt]);
            acc[nt] = mfma16(ah1, bh1, acc[nt]);
            acc[nt] = mfma16(ah0, bl0, acc[nt]);
            acc[nt] = mfma16(ah1, bl1, acc[nt]);
            acc[nt] = mfma16(al0, bh0, acc[nt]);
            acc[nt] = mfma16(al1, bh1, acc[nt]);
        }
    }
    #pragma unroll
    for (int nt = 0; nt < 4; ++nt) {
        const int col = bn*64 + nt*16 + fr;
        const float bv = bias[col];
        #pragma unroll
        for (int i = 0; i < 4; ++i) {
            const int row = bm*64 + w*16 + g*4 + i;
            float v = acc[nt][i] + bv;
            if (ACT == 1) v = fmaxf(v, 0.0f);
            if (ACT == 2) v = tanhf(v);
            const size_t idx = (size_t)row*N + col;
            if (OUTF32) Cf[idx] = v;
            if (OUTBF) {
                const short hh = f2bf(v);
                Chi[idx] = hh;
                Clo[idx] = f2bf(v - bf2f(hh));
            }
        }
    }
}

// ---------------- sparse neighborhood attention ----------------
__global__ __launch_bounds__(64) void nbr_attn_kernel(
    const float* __restrict__ H, const float* __restrict__ An,
    float* __restrict__ H2f, short* __restrict__ H2hi, short* __restrict__ H2lo)
{
    const int i = blockIdx.x;
    const int lane = threadIdx.x;
    const int r = i >> 6, c = i & 63;
    int nbr[8]; int nn = 0;
    for (int dr = -1; dr <= 1; ++dr)
    for (int dc = -1; dc <= 1; ++dc) {
        if (dr == 0 && dc == 0) continue;
        const int rr = r + dr, cc = c + dc;
        if (rr >= 0 && rr < 32 && cc >= 0 && cc < 64) nbr[nn++] = rr*64 + cc;
    }
    float hi[8];
    #pragma unroll
    for (int q = 0; q < 8; ++q) hi[q] = H[(size_t)i*512 + q*64 + lane];
    float logits[8];
    for (int j = 0; j < nn; ++j) {
        const float* an = An + (size_t)nbr[j]*512;
        float s = 0.0f;
        #pragma unroll
        for (int q = 0; q < 8; ++q) s = fmaf(hi[q], an[q*64+lane], s);
        for (int off = 32; off; off >>= 1) s += __shfl_xor(s, off);
        logits[j] = s;
    }
    float mx = -1e30f;
    for (int j = 0; j < nn; ++j) mx = fmaxf(mx, logits[j]);
    float sum = 0.0f; float al[8];
    for (int j = 0; j < nn; ++j) { al[j] = expf(logits[j]-mx); sum += al[j]; }
    const float inv = 1.0f/sum;
    float hn[8] = {};
    for (int j = 0; j < nn; ++j) {
        const float* hj = H + (size_t)nbr[j]*512;
        const float a = al[j]*inv;
        #pragma unroll
        for (int q = 0; q < 8; ++q) hn[q] = fmaf(a, hj[q*64+lane], hn[q]);
    }
    #pragma unroll
    for (int q = 0; q < 8; ++q) {
        const size_t i0 = (size_t)i*1024 + q*64 + lane;
        const size_t i1 = i0 + 512;
        H2f[i0] = hi[q];
        H2f[i1] = hn[q];
        short h0 = f2bf(hi[q]);
        H2hi[i0] = h0; H2lo[i0] = f2bf(hi[q] - bf2f(h0));
        short h1 = f2bf(hn[q]);
        H2hi[i1] = h1; H2lo[i1] = f2bf(hn[q] - bf2f(h1));
    }
}

// ---------------- S[n,t] = P[n,:] . templates[t,:] ----------------
__global__ __launch_bounds__(64) void template_scores_kernel(
    const float* __restrict__ P, const float* __restrict__ Tm, float* __restrict__ S)
{
    const int n = blockIdx.x;
    const int lane = threadIdx.x;
    float p[16];
    #pragma unroll
    for (int q = 0; q < 16; ++q) p[q] = P[(size_t)n*1024 + q*64 + lane];
    for (int t = 0; t < 10; ++t) {
        const float* tm = Tm + t*1024;
        float s = 0.0f;
        #pragma unroll
        for (int q = 0; q < 16; ++q) s = fmaf(p[q], tm[q*64+lane], s);
        for (int off = 32; off; off >>= 1) s += __shfl_xor(s, off);
        if (lane == 0) S[n*10 + t] = s;
    }
}

// ---------------- betas[t,:] = softmax_n(S[:,t]) ----------------
__global__ __launch_bounds__(256) void beta_softmax_kernel(
    const float* __restrict__ S, float* __restrict__ betas)
{
    const int t = blockIdx.x;
    __shared__ float red[256];
    const int tid = threadIdx.x;
    float mx = -1e30f;
    for (int n = tid; n < 2048; n += 256) mx = fmaxf(mx, S[n*10+t]);
    red[tid] = mx; __syncthreads();
    for (int s = 128; s; s >>= 1) { if (tid < s) red[tid] = fmaxf(red[tid], red[tid+s]); __syncthreads(); }
    mx = red[0]; __syncthreads();
    float sum = 0.0f;
    for (int n = tid; n < 2048; n += 256) sum += expf(S[n*10+t]-mx);
    red[tid] = sum; __syncthreads();
    for (int s = 128; s; s >>= 1) { if (tid < s) red[tid] += red[tid+s]; __syncthreads(); }
    const float inv = 1.0f/red[0];
    for (int n = tid; n < 2048; n += 256) betas[t*2048+n] = expf(S[n*10+t]-mx)*inv;
}

__global__ __launch_bounds__(256) void zero_kernel(float* p, int n)
{
    const int i = blockIdx.x*256 + threadIdx.x;
    if (i < n) p[i] = 0.0f;
}

// ---------------- embs[t,:] += betas[t,chunk] @ H2[chunk,:] ----------------
__global__ __launch_bounds__(256) void embs_partial_kernel(
    const float* __restrict__ betas, const float* __restrict__ H2,
    float* __restrict__ embs)
{
    const int t = blockIdx.y;
    const int colc = blockIdx.x & 3;
    const int nc = blockIdx.x >> 2;
    const int col = colc*256 + threadIdx.x;
    const int n0 = nc*256;
    float acc = 0.0f;
    for (int n = n0; n < n0+256; ++n)
        acc = fmaf(betas[t*2048+n], H2[(size_t)n*1024+col], acc);
    atomicAdd(&embs[t*1024+col], acc);
}

// ---------------- g[t] = tanh(embs[t]@gw1^T + gb1) . gw2 ----------------
__global__ __launch_bounds__(256) void glob_g_kernel(
    const float* __restrict__ embs, const float* __restrict__ gw1,
    const float* __restrict__ gb1, const float* __restrict__ gw2,
    float* __restrict__ gvec)
{
    const int t = blockIdx.x;
    __shared__ float red[256];
    const int k = threadIdx.x >> 1;
    const int h = threadIdx.x & 1;
    const float* e  = embs + t*1024 + h*512;
    const float* wv = gw1 + k*1024 + h*512;
    float s = 0.0f;
    for (int q = 0; q < 512; ++q) s = fmaf(e[q], wv[q], s);
    s += __shfl_xor(s, 1);
    red[threadIdx.x] = (h == 0) ? tanhf(s + gb1[k]) * gw2[k] : 0.0f;
    __syncthreads();
    for (int st = 128; st; st >>= 1) {
        if (threadIdx.x < st) red[threadIdx.x] += red[threadIdx.x+st];
        __syncthreads();
    }
    if (threadIdx.x == 0) gvec[t] = red[0];
}

// ---------------- gamma softmax + M + A + classifier ----------------
__global__ __launch_bounds__(256) void final2_kernel(
    const float* __restrict__ gvec, const float* __restrict__ gb2,
    const float* __restrict__ embs, const float* __restrict__ betas,
    const float* __restrict__ cw, const float* __restrict__ cb,
    float* __restrict__ out)
{
    __shared__ float gam[10];
    __shared__ float sM[1024];
    __shared__ float red[256];
    __shared__ float v0s;
    const int tid = threadIdx.x;
    if (tid == 0) {
        float mx = -1e30f;
        for (int t = 0; t < 10; ++t) mx = fmaxf(mx, gvec[t] + gb2[0]);
        float sum = 0.0f;
        for (int t = 0; t < 10; ++t) { gam[t] = expf(gvec[t] + gb2[0] - mx); sum += gam[t]; }
        for (int t = 0; t < 10; ++t) gam[t] /= sum;
    }
    __syncthreads();
    for (int col = tid; col < 1024; col += 256) {
        float m = 0.0f;
        for (int t = 0; t < 10; ++t) m = fmaf(gam[t], embs[t*1024+col], m);
        sM[col] = m;
    }
    for (int n = tid; n < 2048; n += 256) {
        float a = 0.0f;
        for (int t = 0; t < 10; ++t) a = fmaf(gam[t], betas[t*2048+n], a);
        out[3+n] = a;
    }
    __syncthreads();
    float s0 = 0.0f, s1 = 0.0f;
    for (int q = tid; q < 1024; q += 256) {
        s0 = fmaf(sM[q], cw[q], s0);
        s1 = fmaf(sM[q], cw[1024+q], s1);
    }
    red[tid] = s0; __syncthreads();
    for (int s = 128; s; s >>= 1) { if (tid < s) red[tid] += red[tid+s]; __syncthreads(); }
    if (tid == 0) v0s = red[0];
    __syncthreads();
    red[tid] = s1; __syncthreads();
    for (int s = 128; s; s >>= 1) { if (tid < s) red[tid] += red[tid+s]; __syncthreads(); }
    if (tid == 0) {
        const float l0 = v0s + cb[0], l1 = red[0] + cb[1];
        const float p0 = 1.0f/(1.0f+expf(-l0));
        const float p1 = 1.0f/(1.0f+expf(-l1));
        out[0] = p0; out[1] = p1;
        out[2] = (p1 > p0) ? 1.0f : 0.0f;
    }
}

extern "C" void kernel_launch(void* const* d_in, const int* in_sizes, int n_in,
                              void* d_out, int out_size, void* d_ws, size_t ws_size,
                              hipStream_t stream)
{
    (void)in_sizes; (void)n_in; (void)out_size; (void)ws_size;
    const float* x        = (const float*)d_in[0];
    const float* conv1_w  = (const float*)d_in[2];
    const float* conv1_b  = (const float*)d_in[3];
    const float* conv2_w  = (const float*)d_in[4];
    const float* conv2_b  = (const float*)d_in[5];
    const float* fc1_w    = (const float*)d_in[6];
    const float* fc1_b    = (const float*)d_in[7];
    const float* fc2_w    = (const float*)d_in[8];
    const float* fc2_b    = (const float*)d_in[9];
    const float* nbr_w    = (const float*)d_in[10];
    const float* nbr_b    = (const float*)d_in[11];
    const float* templ    = (const float*)d_in[12];
    const float* proto_w  = (const float*)d_in[13];
    const float* proto_b  = (const float*)d_in[14];
    const float* glob_w1  = (const float*)d_in[15];
    const float* glob_b1  = (const float*)d_in[16];
    const float* glob_w2  = (const float*)d_in[17];
    const float* glob_b2  = (const float*)d_in[18];
    const float* cls_w    = (const float*)d_in[19];
    const float* cls_b    = (const float*)d_in[20];
    float* out = (float*)d_out;

    char* p = (char*)d_ws;
    auto alloc = [&](size_t bytes) { char* r = p; p += (bytes + 255) & ~(size_t)255; return r; };
    short* Hfhi   = (short*)alloc((size_t)2048*1728*2);
    short* Hflo   = (short*)alloc((size_t)2048*1728*2);
    short* Hfc1hi = (short*)alloc((size_t)2048*512*2);
    short* Hfc1lo = (short*)alloc((size_t)2048*512*2);
    float* H      = (float*)alloc((size_t)2048*512*4);
    short* Hhi    = (short*)alloc((size_t)2048*512*2);
    short* Hlo    = (short*)alloc((size_t)2048*512*2);
    float* An     = (float*)alloc((size_t)2048*512*4);
    float* H2f    = (float*)alloc((size_t)2048*1024*4);
    short* H2hi   = (short*)alloc((size_t)2048*1024*2);
    short* H2lo   = (short*)alloc((size_t)2048*1024*2);
    float* P      = (float*)alloc((size_t)2048*1024*4);
    float* S      = (float*)alloc((size_t)2048*10*4);
    float* betas  = (float*)alloc((size_t)10*2048*4);
    float* embs   = (float*)alloc((size_t)10*1024*4);
    float* gvec   = (float*)alloc(64);
    short* w1m    = (short*)alloc(1536*2);
    short* w2m    = (short*)alloc(27648*2);
    short* fc1whi = (short*)alloc((size_t)512*1728*2);
    short* fc1wlo = (short*)alloc((size_t)512*1728*2);
    short* fc2whi = (short*)alloc((size_t)512*512*2);
    short* fc2wlo = (short*)alloc((size_t)512*512*2);
    short* nbrwhi = (short*)alloc((size_t)512*512*2);
    short* nbrwlo = (short*)alloc((size_t)512*512*2);
    short* prwhi  = (short*)alloc((size_t)1024*1024*2);
    short* prwlo  = (short*)alloc((size_t)1024*1024*2);

    // weight prep
    split_cast_kernel<<<(884736+255)/256, 256, 0, stream>>>(fc1_w, fc1whi, fc1wlo, 884736);
    split_cast_kernel<<<(262144+255)/256, 256, 0, stream>>>(fc2_w, fc2whi, fc2wlo, 262144);
    split_cast_kernel<<<(262144+255)/256, 256, 0, stream>>>(nbr_w, nbrwhi, nbrwlo, 262144);
    split_cast_kernel<<<(1048576+255)/256, 256, 0, stream>>>(proto_w, prwhi, prwlo, 1048576);
    prep_w1m_kernel<<<24, 64, 0, stream>>>(conv1_w, w1m);
    prep_w2m_kernel<<<108, 256, 0, stream>>>(conv2_w, w2m);

    conv_mfma_kernel<<<2048, 256, 0, stream>>>(x, w1m, conv1_b, w2m, conv2_b, Hfhi, Hflo);
    gemm_split_kernel<1,0,1><<<dim3(8,32), 256, 0, stream>>>(
        Hfhi, Hflo, fc1whi, fc1wlo, fc1_b, nullptr, Hfc1hi, Hfc1lo, 512, 1728);
    gemm_split_kernel<1,1,1><<<dim3(8,32), 256, 0, stream>>>(
        Hfc1hi, Hfc1lo, fc2whi, fc2wlo, fc2_b, H, Hhi, Hlo, 512, 512);
    gemm_split_kernel<2,1,0><<<dim3(8,32), 256, 0, stream>>>(
        Hhi, Hlo, nbrwhi, nbrwlo, nbr_b, An, nullptr, nullptr, 512, 512);
    nbr_attn_kernel<<<2048, 64, 0, stream>>>(H, An, H2f, H2hi, H2lo);
    gemm_split_kernel<2,1,0><<<dim3(16,32), 256, 0, stream>>>(
        H2hi, H2lo, prwhi, prwlo, proto_b, P, nullptr, nullptr, 1024, 1024);
    template_scores_kernel<<<2048, 64, 0, stream>>>(P, templ, S);
    beta_softmax_kernel<<<10, 256, 0, stream>>>(S, betas);
    zero_kernel<<<40, 256, 0, stream>>>(embs, 10240);
    embs_partial_kernel<<<dim3(32,10), 256, 0, stream>>>(betas, H2f, embs);
    glob_g_kernel<<<10, 256, 0, stream>>>(embs, glob_w1, glob_b1, glob_w2, gvec);
    final2_kernel<<<1, 256, 0, stream>>>(gvec, glob_b2, embs, betas, cls_w, cls_b, out);
}

// Round 4
// 290.924 us; speedup vs baseline: 3.1826x; 1.1743x over previous
//
#include <hip/hip_runtime.h>
#include <hip/hip_bf16.h>
#include <math.h>

// ---------------------------------------------------------------------------
// MAMIL round 4: conv_mfma latency fix.
//  - x staged coalesced into LDS (4KB), conv1 A-frags built directly from it
//    (no win[] im2col buffer, no scattered scalar global loads, 2 barriers)
//  - conv2 nt-outer (18-frag B reload per nt) -> VGPR<=128
//  - __launch_bounds__(256,4): 29.2KB LDS + 128 VGPR -> 4 blocks/CU
// GEMM chain unchanged from round 3 (split-bf16 MFMA, absmax 3.9e-3).
// ---------------------------------------------------------------------------

typedef short short8 __attribute__((ext_vector_type(8)));
typedef float f32x4  __attribute__((ext_vector_type(4)));

__device__ inline short f2bf(float f) {
    unsigned u = __builtin_bit_cast(unsigned, f);
    u += 0x7fff + ((u >> 16) & 1);
    return (short)(u >> 16);
}
__device__ inline float bf2f(short h) {
    unsigned u = ((unsigned)(unsigned short)h) << 16;
    return __builtin_bit_cast(float, u);
}
__device__ inline f32x4 mfma16(short8 a, short8 b, f32x4 c) {
    return __builtin_amdgcn_mfma_f32_16x16x32_bf16(a, b, c, 0, 0, 0);
}

// ---------------- weight prep ----------------
__global__ __launch_bounds__(256) void split_cast_kernel(
    const float* __restrict__ s, short* __restrict__ hi, short* __restrict__ lo, int n)
{
    int i = blockIdx.x*256 + threadIdx.x;
    if (i < n) {
        float f = s[i];
        short h = f2bf(f);
        hi[i] = h;
        lo[i] = f2bf(f - bf2f(h));
    }
}

__global__ __launch_bounds__(64) void prep_w1m_kernel(
    const float* __restrict__ w1, short* __restrict__ w1m)   // [48][32]
{
    int i = blockIdx.x*64 + threadIdx.x;
    if (i < 1536) {
        int c = i >> 5, k = i & 31;
        w1m[i] = (c < 36 && k < 16) ? f2bf(w1[c*16 + k]) : (short)0;
    }
}

__global__ __launch_bounds__(256) void prep_w2m_kernel(
    const float* __restrict__ w2, short* __restrict__ w2m)   // [48][576], k=tap*64+ic
{
    int i = blockIdx.x*256 + threadIdx.x;
    if (i < 27648) {
        int oc = i / 576, r = i % 576, tap = r >> 6, c = r & 63;
        w2m[i] = (c < 36) ? f2bf(w2[oc*324 + c*9 + tap]) : (short)0;
    }
}

// ---------------- fused conv1+pool -> conv2+pool (MFMA) ----------------
// im2col row order p' = pooledpos*4 + (dy*2+dx): each 16-row M-tile = 4 pooled
// positions; D-frag row = (lane>>4)*4+i, so pool = max over the 4 acc regs.
__global__ __launch_bounds__(256, 4) void conv_mfma_kernel(
    const float* __restrict__ x,     // [2048][1024]
    const short* __restrict__ w1m,   // [48][32]
    const float* __restrict__ b1,    // [36]
    const short* __restrict__ w2m,   // [48][576]
    const float* __restrict__ b2,    // [48]
    short* __restrict__ Hfhi, short* __restrict__ Hflo)  // [2048][1728], oc*36+r2
{
    __shared__ __align__(16) float sx[1024];      // raw input image
    __shared__ __align__(16) short sh1[196*64];   // [h1row][64] ic-padded, swz ((row&7)<<4)
    const int n = blockIdx.x, tid = threadIdx.x;
    const int l = tid & 63, w = tid >> 6, g = l >> 4, fr = l & 15;

    // stage x coalesced (one float4 per thread)
    ((float4*)sx)[tid] = ((const float4*)(x + (size_t)n*1024))[tid];
    // zero sh1 (padding cols must be 0)
    {
        short8 z = {};
        for (int i = tid; i < 196*64/8; i += 256) *(short8*)&sh1[i*8] = z;
    }
    // conv1 B-frags from global (L2), cached in regs
    short8 bw1[3];
    #pragma unroll
    for (int nt = 0; nt < 3; ++nt)
        bw1[nt] = *(const short8*)(w1m + (nt*16 + fr)*32 + g*8);
    __syncthreads();

    // ---- conv1 (1->36, 4x4, VALID 32->29) + relu + 2x2 pool -> [196][64] ----
    // lane (g,fr) of tile mt supplies A row pp=mt*16+fr, k=g*8..g*8+7:
    //   g=0 -> window rows 0,1; g=1 -> rows 2,3; g>=2 -> zero pad (K 16->32)
    for (int mt = w; mt < 49; mt += 4) {
        const int pp = mt*16 + fr;
        const int q = pp >> 2, dd = pp & 3;
        const int iy0 = 2*(q/14) + (dd >> 1), ix0 = 2*(q%14) + (dd & 1);
        short8 af = {};
        if (g < 2) {
            const float* r0 = &sx[(iy0 + 2*g)*32 + ix0];
            const float* r1 = r0 + 32;
            af[0] = f2bf(r0[0]); af[1] = f2bf(r0[1]);
            af[2] = f2bf(r0[2]); af[3] = f2bf(r0[3]);
            af[4] = f2bf(r1[0]); af[5] = f2bf(r1[1]);
            af[6] = f2bf(r1[2]); af[7] = f2bf(r1[3]);
        }
        f32x4 acc[3] = {};
        #pragma unroll
        for (int nt = 0; nt < 3; ++nt) acc[nt] = mfma16(af, bw1[nt], acc[nt]);
        const int q1 = mt*4 + g;          // pooled pos 0..195
        #pragma unroll
        for (int nt = 0; nt < 3; ++nt) {
            const int c = nt*16 + fr;
            if (c < 36) {
                float m = fmaxf(fmaxf(acc[nt][0], acc[nt][1]),
                                fmaxf(acc[nt][2], acc[nt][3]));
                m = fmaxf(m + b1[c], 0.0f);
                *(short*)((char*)sh1 + ((q1*128 + c*2) ^ ((q1 & 7) << 4))) = f2bf(m);
            }
        }
    }
    __syncthreads();   // sh1 complete

    // ---- conv2: M=144 (p' = pooled*4+quad), N=48, K=18 steps of 32 ----
    // wave w handles mt in {w, w+4, w+8(<9)}; nt-outer so B-frags (18) reload
    const int nmt = (w == 0) ? 3 : 2;
    #pragma unroll
    for (int nt = 0; nt < 3; ++nt) {
        short8 bfr[18];
        {
            const short* wb = w2m + (size_t)(nt*16 + fr)*576 + g*8;
            #pragma unroll
            for (int ks = 0; ks < 18; ++ks)
                bfr[ks] = *(const short8*)(wb + ks*32);
        }
        for (int mi = 0; mi < nmt; ++mi) {
            const int mt = w + mi*4;
            const int pp = mt*16 + fr;
            const int q2 = pp >> 2, dd = pp & 3;
            const int oy = 2*(q2/6) + (dd >> 1), ox = 2*(q2%6) + (dd & 1);
            f32x4 acc = {};
            #pragma unroll
            for (int ks = 0; ks < 18; ++ks) {
                const int tap = ks >> 1, half = ks & 1;
                const int hr = (oy + tap/3)*14 + ox + tap%3;
                const short8 a = *(const short8*)((char*)sh1 +
                    ((hr*128 + half*64 + g*16) ^ ((hr & 7) << 4)));
                acc = mfma16(a, bfr[ks], acc);
            }
            const int oc = nt*16 + fr;
            float m = fmaxf(fmaxf(acc[0], acc[1]), fmaxf(acc[2], acc[3]));
            m = fmaxf(m + b2[oc], 0.0f);
            const size_t idx = (size_t)n*1728 + oc*36 + (mt*4 + g);
            const short hh = f2bf(m);
            Hfhi[idx] = hh;
            Hflo[idx] = f2bf(m - bf2f(hh));
        }
    }
}

// ---------------- split-bf16 MFMA GEMM: C = act(A @ W^T + bias) ----------------
// A,W given as bf16 hi/lo planes [M][K],[N][K]. M%64==0, N%64==0, K%64==0.
template<int ACT, int OUTF32, int OUTBF>
__global__ __launch_bounds__(256) void gemm_split_kernel(
    const short* __restrict__ Ahi, const short* __restrict__ Alo,
    const short* __restrict__ Whi, const short* __restrict__ Wlo,
    const float* __restrict__ bias,
    float* __restrict__ Cf, short* __restrict__ Chi, short* __restrict__ Clo,
    const int N, const int K)
{
    __shared__ __align__(16) short sA[2][4096];   // [hi/lo][row*64+k], swz ((row&7)<<4)
    __shared__ __align__(16) short sB[2][4096];
    const int bn = blockIdx.x, bm = blockIdx.y;
    const int tid = threadIdx.x, l = tid & 63, w = tid >> 6, g = l >> 4, fr = l & 15;
    const int srow = tid >> 2, kc = (tid & 3) << 4;
    const size_t aoff = (size_t)(bm*64 + srow)*K + kc;
    const size_t boff = (size_t)(bn*64 + srow)*K + kc;
    const int swb = (srow & 7) << 4;
    const int wbase = srow*128 + kc*2;
    f32x4 acc[4] = {};
    for (int k0 = 0; k0 < K; k0 += 64) {
        const short8 a0 = *(const short8*)(Ahi + aoff + k0);
        const short8 a1 = *(const short8*)(Ahi + aoff + k0 + 8);
        const short8 a2 = *(const short8*)(Alo + aoff + k0);
        const short8 a3 = *(const short8*)(Alo + aoff + k0 + 8);
        const short8 b0 = *(const short8*)(Whi + boff + k0);
        const short8 b1 = *(const short8*)(Whi + boff + k0 + 8);
        const short8 b2 = *(const short8*)(Wlo + boff + k0);
        const short8 b3 = *(const short8*)(Wlo + boff + k0 + 8);
        __syncthreads();
        *(short8*)((char*)&sA[0][0] + ((wbase     ) ^ swb)) = a0;
        *(short8*)((char*)&sA[0][0] + ((wbase + 16) ^ swb)) = a1;
        *(short8*)((char*)&sA[1][0] + ((wbase     ) ^ swb)) = a2;
        *(short8*)((char*)&sA[1][0] + ((wbase + 16) ^ swb)) = a3;
        *(short8*)((char*)&sB[0][0] + ((wbase     ) ^ swb)) = b0;
        *(short8*)((char*)&sB[0][0] + ((wbase + 16) ^ swb)) = b1;
        *(short8*)((char*)&sB[1][0] + ((wbase     ) ^ swb)) = b2;
        *(short8*)((char*)&sB[1][0] + ((wbase + 16) ^ swb)) = b3;
        __syncthreads();
        const int ar = w*16 + fr, asw = (ar & 7) << 4;
        const short8 ah0 = *(const short8*)((char*)&sA[0][0] + ((ar*128      + g*16) ^ asw));
        const short8 ah1 = *(const short8*)((char*)&sA[0][0] + ((ar*128 + 64 + g*16) ^ asw));
        const short8 al0 = *(const short8*)((char*)&sA[1][0] + ((ar*128      + g*16) ^ asw));
        const short8 al1 = *(const short8*)((char*)&sA[1][0] + ((ar*128 + 64 + g*16) ^ asw));
        #pragma unroll
        for (int nt = 0; nt < 4; ++nt) {
            const int br = nt*16 + fr, bsw = (br & 7) << 4;
            const short8 bh0 = *(const short8*)((char*)&sB[0][0] + ((br*128      + g*16) ^ bsw));
            const short8 bh1 = *(const short8*)((char*)&sB[0][0] + ((br*128 + 64 + g*16) ^ bsw));
            const short8 bl0 = *(const short8*)((char*)&sB[1][0] + ((br*128      + g*16) ^ bsw));
            const short8 bl1 = *(const short8*)((char*)&sB[1][0] + ((br*128 + 64 + g*16) ^ bsw));
            acc[nt] = mfma16(ah0, bh0, acc[nt]);
            acc[nt] = mfma16(ah1, bh1, acc[nt]);
            acc[nt] = mfma16(ah0, bl0, acc[nt]);
            acc[nt] = mfma16(ah1, bl1, acc[nt]);
            acc[nt] = mfma16(al0, bh0, acc[nt]);
            acc[nt] = mfma16(al1, bh1, acc[nt]);
        }
    }
    #pragma unroll
    for (int nt = 0; nt < 4; ++nt) {
        const int col = bn*64 + nt*16 + fr;
        const float bv = bias[col];
        #pragma unroll
        for (int i = 0; i < 4; ++i) {
            const int row = bm*64 + w*16 + g*4 + i;
            float v = acc[nt][i] + bv;
            if (ACT == 1) v = fmaxf(v, 0.0f);
            if (ACT == 2) v = tanhf(v);
            const size_t idx = (size_t)row*N + col;
            if (OUTF32) Cf[idx] = v;
            if (OUTBF) {
                const short hh = f2bf(v);
                Chi[idx] = hh;
                Clo[idx] = f2bf(v - bf2f(hh));
            }
        }
    }
}

// ---------------- sparse neighborhood attention ----------------
__global__ __launch_bounds__(64) void nbr_attn_kernel(
    const float* __restrict__ H, const float* __restrict__ An,
    float* __restrict__ H2f, short* __restrict__ H2hi, short* __restrict__ H2lo)
{
    const int i = blockIdx.x;
    const int lane = threadIdx.x;
    const int r = i >> 6, c = i & 63;
    int nbr[8]; int nn = 0;
    for (int dr = -1; dr <= 1; ++dr)
    for (int dc = -1; dc <= 1; ++dc) {
        if (dr == 0 && dc == 0) continue;
        const int rr = r + dr, cc = c + dc;
        if (rr >= 0 && rr < 32 && cc >= 0 && cc < 64) nbr[nn++] = rr*64 + cc;
    }
    float hi[8];
    #pragma unroll
    for (int q = 0; q < 8; ++q) hi[q] = H[(size_t)i*512 + q*64 + lane];
    float logits[8];
    for (int j = 0; j < nn; ++j) {
        const float* an = An + (size_t)nbr[j]*512;
        float s = 0.0f;
        #pragma unroll
        for (int q = 0; q < 8; ++q) s = fmaf(hi[q], an[q*64+lane], s);
        for (int off = 32; off; off >>= 1) s += __shfl_xor(s, off);
        logits[j] = s;
    }
    float mx = -1e30f;
    for (int j = 0; j < nn; ++j) mx = fmaxf(mx, logits[j]);
    float sum = 0.0f; float al[8];
    for (int j = 0; j < nn; ++j) { al[j] = expf(logits[j]-mx); sum += al[j]; }
    const float inv = 1.0f/sum;
    float hn[8] = {};
    for (int j = 0; j < nn; ++j) {
        const float* hj = H + (size_t)nbr[j]*512;
        const float a = al[j]*inv;
        #pragma unroll
        for (int q = 0; q < 8; ++q) hn[q] = fmaf(a, hj[q*64+lane], hn[q]);
    }
    #pragma unroll
    for (int q = 0; q < 8; ++q) {
        const size_t i0 = (size_t)i*1024 + q*64 + lane;
        const size_t i1 = i0 + 512;
        H2f[i0] = hi[q];
        H2f[i1] = hn[q];
        short h0 = f2bf(hi[q]);
        H2hi[i0] = h0; H2lo[i0] = f2bf(hi[q] - bf2f(h0));
        short h1 = f2bf(hn[q]);
        H2hi[i1] = h1; H2lo[i1] = f2bf(hn[q] - bf2f(h1));
    }
}

// ---------------- S[n,t] = P[n,:] . templates[t,:] ----------------
__global__ __launch_bounds__(64) void template_scores_kernel(
    const float* __restrict__ P, const float* __restrict__ Tm, float* __restrict__ S)
{
    const int n = blockIdx.x;
    const int lane = threadIdx.x;
    float p[16];
    #pragma unroll
    for (int q = 0; q < 16; ++q) p[q] = P[(size_t)n*1024 + q*64 + lane];
    for (int t = 0; t < 10; ++t) {
        const float* tm = Tm + t*1024;
        float s = 0.0f;
        #pragma unroll
        for (int q = 0; q < 16; ++q) s = fmaf(p[q], tm[q*64+lane], s);
        for (int off = 32; off; off >>= 1) s += __shfl_xor(s, off);
        if (lane == 0) S[n*10 + t] = s;
    }
}

// ---------------- betas[t,:] = softmax_n(S[:,t]) ----------------
__global__ __launch_bounds__(256) void beta_softmax_kernel(
    const float* __restrict__ S, float* __restrict__ betas)
{
    const int t = blockIdx.x;
    __shared__ float red[256];
    const int tid = threadIdx.x;
    float mx = -1e30f;
    for (int n = tid; n < 2048; n += 256) mx = fmaxf(mx, S[n*10+t]);
    red[tid] = mx; __syncthreads();
    for (int s = 128; s; s >>= 1) { if (tid < s) red[tid] = fmaxf(red[tid], red[tid+s]); __syncthreads(); }
    mx = red[0]; __syncthreads();
    float sum = 0.0f;
    for (int n = tid; n < 2048; n += 256) sum += expf(S[n*10+t]-mx);
    red[tid] = sum; __syncthreads();
    for (int s = 128; s; s >>= 1) { if (tid < s) red[tid] += red[tid+s]; __syncthreads(); }
    const float inv = 1.0f/red[0];
    for (int n = tid; n < 2048; n += 256) betas[t*2048+n] = expf(S[n*10+t]-mx)*inv;
}

__global__ __launch_bounds__(256) void zero_kernel(float* p, int n)
{
    const int i = blockIdx.x*256 + threadIdx.x;
    if (i < n) p[i] = 0.0f;
}

// ---------------- embs[t,:] += betas[t,chunk] @ H2[chunk,:] ----------------
__global__ __launch_bounds__(256) void embs_partial_kernel(
    const float* __restrict__ betas, const float* __restrict__ H2,
    float* __restrict__ embs)
{
    const int t = blockIdx.y;
    const int colc = blockIdx.x & 3;
    const int nc = blockIdx.x >> 2;
    const int col = colc*256 + threadIdx.x;
    const int n0 = nc*256;
    float acc = 0.0f;
    for (int n = n0; n < n0+256; ++n)
        acc = fmaf(betas[t*2048+n], H2[(size_t)n*1024+col], acc);
    atomicAdd(&embs[t*1024+col], acc);
}

// ---------------- g[t] = tanh(embs[t]@gw1^T + gb1) . gw2 ----------------
__global__ __launch_bounds__(256) void glob_g_kernel(
    const float* __restrict__ embs, const float* __restrict__ gw1,
    const float* __restrict__ gb1, const float* __restrict__ gw2,
    float* __restrict__ gvec)
{
    const int t = blockIdx.x;
    __shared__ float red[256];
    const int k = threadIdx.x >> 1;
    const int h = threadIdx.x & 1;
    const float* e  = embs + t*1024 + h*512;
    const float* wv = gw1 + k*1024 + h*512;
    float s = 0.0f;
    for (int q = 0; q < 512; ++q) s = fmaf(e[q], wv[q], s);
    s += __shfl_xor(s, 1);
    red[threadIdx.x] = (h == 0) ? tanhf(s + gb1[k]) * gw2[k] : 0.0f;
    __syncthreads();
    for (int st = 128; st; st >>= 1) {
        if (threadIdx.x < st) red[threadIdx.x] += red[threadIdx.x+st];
        __syncthreads();
    }
    if (threadIdx.x == 0) gvec[t] = red[0];
}

// ---------------- gamma softmax + M + A + classifier ----------------
__global__ __launch_bounds__(256) void final2_kernel(
    const float* __restrict__ gvec, const float* __restrict__ gb2,
    const float* __restrict__ embs, const float* __restrict__ betas,
    const float* __restrict__ cw, const float* __restrict__ cb,
    float* __restrict__ out)
{
    __shared__ float gam[10];
    __shared__ float sM[1024];
    __shared__ float red[256];
    __shared__ float v0s;
    const int tid = threadIdx.x;
    if (tid == 0) {
        float mx = -1e30f;
        for (int t = 0; t < 10; ++t) mx = fmaxf(mx, gvec[t] + gb2[0]);
        float sum = 0.0f;
        for (int t = 0; t < 10; ++t) { gam[t] = expf(gvec[t] + gb2[0] - mx); sum += gam[t]; }
        for (int t = 0; t < 10; ++t) gam[t] /= sum;
    }
    __syncthreads();
    for (int col = tid; col < 1024; col += 256) {
        float m = 0.0f;
        for (int t = 0; t < 10; ++t) m = fmaf(gam[t], embs[t*1024+col], m);
        sM[col] = m;
    }
    for (int n = tid; n < 2048; n += 256) {
        float a = 0.0f;
        for (int t = 0; t < 10; ++t) a = fmaf(gam[t], betas[t*2048+n], a);
        out[3+n] = a;
    }
    __syncthreads();
    float s0 = 0.0f, s1 = 0.0f;
    for (int q = tid; q < 1024; q += 256) {
        s0 = fmaf(sM[q], cw[q], s0);
        s1 = fmaf(sM[q], cw[1024+q], s1);
    }
    red[tid] = s0; __syncthreads();
    for (int s = 128; s; s >>= 1) { if (tid < s) red[tid] += red[tid+s]; __syncthreads(); }
    if (tid == 0) v0s = red[0];
    __syncthreads();
    red[tid] = s1; __syncthreads();
    for (int s = 128; s; s >>= 1) { if (tid < s) red[tid] += red[tid+s]; __syncthreads(); }
    if (tid == 0) {
        const float l0 = v0s + cb[0], l1 = red[0] + cb[1];
        const float p0 = 1.0f/(1.0f+expf(-l0));
        const float p1 = 1.0f/(1.0f+expf(-l1));
        out[0] = p0; out[1] = p1;
        out[2] = (p1 > p0) ? 1.0f : 0.0f;
    }
}

extern "C" void kernel_launch(void* const* d_in, const int* in_sizes, int n_in,
                              void* d_out, int out_size, void* d_ws, size_t ws_size,
                              hipStream_t stream)
{
    (void)in_sizes; (void)n_in; (void)out_size; (void)ws_size;
    const float* x        = (const float*)d_in[0];
    const float* conv1_w  = (const float*)d_in[2];
    const float* conv1_b  = (const float*)d_in[3];
    const float* conv2_w  = (const float*)d_in[4];
    const float* conv2_b  = (const float*)d_in[5];
    const float* fc1_w    = (const float*)d_in[6];
    const float* fc1_b    = (const float*)d_in[7];
    const float* fc2_w    = (const float*)d_in[8];
    const float* fc2_b    = (const float*)d_in[9];
    const float* nbr_w    = (const float*)d_in[10];
    const float* nbr_b    = (const float*)d_in[11];
    const float* templ    = (const float*)d_in[12];
    const float* proto_w  = (const float*)d_in[13];
    const float* proto_b  = (const float*)d_in[14];
    const float* glob_w1  = (const float*)d_in[15];
    const float* glob_b1  = (const float*)d_in[16];
    const float* glob_w2  = (const float*)d_in[17];
    const float* glob_b2  = (const float*)d_in[18];
    const float* cls_w    = (const float*)d_in[19];
    const float* cls_b    = (const float*)d_in[20];
    float* out = (float*)d_out;

    char* p = (char*)d_ws;
    auto alloc = [&](size_t bytes) { char* r = p; p += (bytes + 255) & ~(size_t)255; return r; };
    short* Hfhi   = (short*)alloc((size_t)2048*1728*2);
    short* Hflo   = (short*)alloc((size_t)2048*1728*2);
    short* Hfc1hi = (short*)alloc((size_t)2048*512*2);
    short* Hfc1lo = (short*)alloc((size_t)2048*512*2);
    float* H      = (float*)alloc((size_t)2048*512*4);
    short* Hhi    = (short*)alloc((size_t)2048*512*2);
    short* Hlo    = (short*)alloc((size_t)2048*512*2);
    float* An     = (float*)alloc((size_t)2048*512*4);
    float* H2f    = (float*)alloc((size_t)2048*1024*4);
    short* H2hi   = (short*)alloc((size_t)2048*1024*2);
    short* H2lo   = (short*)alloc((size_t)2048*1024*2);
    float* P      = (float*)alloc((size_t)2048*1024*4);
    float* S      = (float*)alloc((size_t)2048*10*4);
    float* betas  = (float*)alloc((size_t)10*2048*4);
    float* embs   = (float*)alloc((size_t)10*1024*4);
    float* gvec   = (float*)alloc(64);
    short* w1m    = (short*)alloc(1536*2);
    short* w2m    = (short*)alloc(27648*2);
    short* fc1whi = (short*)alloc((size_t)512*1728*2);
    short* fc1wlo = (short*)alloc((size_t)512*1728*2);
    short* fc2whi = (short*)alloc((size_t)512*512*2);
    short* fc2wlo = (short*)alloc((size_t)512*512*2);
    short* nbrwhi = (short*)alloc((size_t)512*512*2);
    short* nbrwlo = (short*)alloc((size_t)512*512*2);
    short* prwhi  = (short*)alloc((size_t)1024*1024*2);
    short* prwlo  = (short*)alloc((size_t)1024*1024*2);

    // weight prep
    split_cast_kernel<<<(884736+255)/256, 256, 0, stream>>>(fc1_w, fc1whi, fc1wlo, 884736);
    split_cast_kernel<<<(262144+255)/256, 256, 0, stream>>>(fc2_w, fc2whi, fc2wlo, 262144);
    split_cast_kernel<<<(262144+255)/256, 256, 0, stream>>>(nbr_w, nbrwhi, nbrwlo, 262144);
    split_cast_kernel<<<(1048576+255)/256, 256, 0, stream>>>(proto_w, prwhi, prwlo, 1048576);
    prep_w1m_kernel<<<24, 64, 0, stream>>>(conv1_w, w1m);
    prep_w2m_kernel<<<108, 256, 0, stream>>>(conv2_w, w2m);

    conv_mfma_kernel<<<2048, 256, 0, stream>>>(x, w1m, conv1_b, w2m, conv2_b, Hfhi, Hflo);
    gemm_split_kernel<1,0,1><<<dim3(8,32), 256, 0, stream>>>(
        Hfhi, Hflo, fc1whi, fc1wlo, fc1_b, nullptr, Hfc1hi, Hfc1lo, 512, 1728);
    gemm_split_kernel<1,1,1><<<dim3(8,32), 256, 0, stream>>>(
        Hfc1hi, Hfc1lo, fc2whi, fc2wlo, fc2_b, H, Hhi, Hlo, 512, 512);
    gemm_split_kernel<2,1,0><<<dim3(8,32), 256, 0, stream>>>(
        Hhi, Hlo, nbrwhi, nbrwlo, nbr_b, An, nullptr, nullptr, 512, 512);
    nbr_attn_kernel<<<2048, 64, 0, stream>>>(H, An, H2f, H2hi, H2lo);
    gemm_split_kernel<2,1,0><<<dim3(16,32), 256, 0, stream>>>(
        H2hi, H2lo, prwhi, prwlo, proto_b, P, nullptr, nullptr, 1024, 1024);
    template_scores_kernel<<<2048, 64, 0, stream>>>(P, templ, S);
    beta_softmax_kernel<<<10, 256, 0, stream>>>(S, betas);
    zero_kernel<<<40, 256, 0, stream>>>(embs, 10240);
    embs_partial_kernel<<<dim3(32,10), 256, 0, stream>>>(betas, H2f, embs);
    glob_g_kernel<<<10, 256, 0, stream>>>(embs, glob_w1, glob_b1, glob_w2, gvec);
    final2_kernel<<<1, 256, 0, stream>>>(gvec, glob_b2, embs, betas, cls_w, cls_b, out);
}